// Round 14
// baseline (131.217 us; speedup 1.0000x reference)
//
#include <hip/hip_runtime.h>
#include <hip/hip_bf16.h>

#define T_LEN 4096
#define EMB   1024
#define HDIM  128
#define QSCALE 0.12752039955379307f   // (1/sqrt(128)) * log2(e) -- folded into Q

typedef __attribute__((ext_vector_type(8))) short bf16x8;
typedef __attribute__((ext_vector_type(4))) short s16x4;
typedef __attribute__((ext_vector_type(4))) float f32x4;
typedef __attribute__((ext_vector_type(16))) float f32x16;
typedef __attribute__((ext_vector_type(4))) unsigned u32x4;

__device__ __forceinline__ short f2bf(float f) {
    unsigned u = __builtin_bit_cast(unsigned, f);
    u += 0x7fffu + ((u >> 16) & 1u);   // RNE
    return (short)(u >> 16);
}
__device__ __forceinline__ float bf2f(short s) {
    unsigned u = ((unsigned)(unsigned short)s) << 16;
    return __builtin_bit_cast(float, u);
}

__device__ __forceinline__ unsigned cvt_pk_bf16(float lo, float hi) {
    unsigned r;
    asm("v_cvt_pk_bf16_f32 %0, %1, %2" : "=v"(r) : "v"(lo), "v"(hi));
    return r;
}

// exchange a.hi32lanes <-> b.lo32lanes (T12)
__device__ __forceinline__ void plswap(unsigned &a, unsigned &b) {
#if __has_builtin(__builtin_amdgcn_permlane32_swap)
    auto r = __builtin_amdgcn_permlane32_swap(a, b, false, false);
    a = r[0]; b = r[1];
#else
    asm volatile("v_permlane32_swap_b32 %0, %1" : "+v"(a), "+v"(b));
#endif
}

__device__ __forceinline__ bf16x8 mk8(unsigned a, unsigned b, unsigned c, unsigned d) {
    u32x4 v = {a, b, c, d};
    return __builtin_bit_cast(bf16x8, v);
}

// async global->LDS DMA, 16B/lane; lds ptr = wave-uniform base (HW adds lane*16)
__device__ __forceinline__ void gload16(const short* g, const char* l) {
    __builtin_amdgcn_global_load_lds(
        (const __attribute__((address_space(1))) unsigned*)g,
        (__attribute__((address_space(3))) unsigned*)l, 16, 0, 0);
}

// pieces for query-row j (256 queries, L=4j+4 key tiles), max 11 tiles/piece
__device__ __forceinline__ int pieces_of(int j) { return (4 * j + 14) / 11; }

// ---------------- fused prep: pe table + x cvt + 3 weight transposes ----------------
__global__ __launch_bounds__(256)
void prep_kernel(const float* __restrict__ x, const float* __restrict__ Wq,
                 const float* __restrict__ Wkv, const float* __restrict__ Wo,
                 float* __restrict__ pe, short* __restrict__ xb,
                 short* __restrict__ wt, short* __restrict__ wot) {
    __shared__ short t[32][33];
    int b = blockIdx.x;
    if (b < 1024) {                            // PE table
        int idx = b * 256 + threadIdx.x;
        int tt = idx >> 6, i = idx & 63;
        float f = __expf(-9.210340371976184f * (float)i / 64.0f);
        float a = (float)tt * f;
        pe[tt * HDIM + 2 * i]     = __sinf(a);
        pe[tt * HDIM + 2 * i + 1] = __cosf(a);
        return;
    }
    b -= 1024;
    if (b < 4096) {                            // x f32 -> bf16
        int e0 = (b * 256 + threadIdx.x) * 4;
        f32x4 v = *(const f32x4*)(x + e0);
        s16x4 o;
        for (int j = 0; j < 4; ++j) o[j] = f2bf(v[j]);
        *(s16x4*)(xb + e0) = o;
        return;
    }
    b -= 4096;                                 // f32 [1024][C] -> bf16 [C][1024]
    const float* src; short* dst; int C, sub;
    if (b < 1024)      { src = Wq;  dst = wt;               C = 1024; sub = b; }
    else if (b < 1280) { src = Wkv; dst = wt + 1024 * 1024; C = 256;  sub = b - 1024; }
    else               { src = Wo;  dst = wot;              C = 1024; sub = b - 1280; }
    const int r0 = (sub & 31) * 32, c0 = (sub >> 5) * 32;
    const int tr = threadIdx.x >> 3, tc4 = (threadIdx.x & 7) * 4;
    f32x4 v = *(const f32x4*)(src + (long)(r0 + tr) * C + c0 + tc4);
    for (int j = 0; j < 4; ++j) t[tc4 + j][tr] = f2bf(v[j]);
    __syncthreads();
    s16x4 o;
    for (int j = 0; j < 4; ++j) o[j] = t[tr][tc4 + j];
    *(s16x4*)(dst + (long)(c0 + tr) * 1024 + r0 + tc4) = o;
}

// ---------------- bf16 MFMA GEMM: 128x128 tile, BK=64, dbuf global_load_lds ----------------
// m97-class structure: 0.5 LDS b128 reads per MFMA (was 0.75 at 128x64), 32 MFMA/wave
// per barrier drain. LDS 64KB -> 2 blocks/CU; acc[4][4]=64 VGPR, total ~115 (<=128).
template<int MODE>
__global__ __launch_bounds__(256)
void gemm_kernel(const short* __restrict__ A, const short* __restrict__ Bt,
                 const float* __restrict__ bq, const float* __restrict__ bkv,
                 const float* __restrict__ pe,
                 short* __restrict__ Qb, short* __restrict__ Kb, short* __restrict__ Vtb,
                 float* __restrict__ Cout) {
    const int tid = threadIdx.x, lane = tid & 63, wid = tid >> 6;
    const int l15 = lane & 15, lk = lane >> 4;
    const int m0 = blockIdx.x * 128, n0 = blockIdx.y * 128;
    const int wr = (wid >> 1) * 64, wc = (wid & 1) * 64;

    __shared__ __align__(16) short As[2][128 * 64];   // 16KB per buf
    __shared__ __align__(16) short Bs[2][128 * 64];   // 16KB per buf

#define GSTAGE(buf, k0) do {                                                            \
    _Pragma("unroll") for (int i_ = 0; i_ < 4; ++i_) {                                  \
        int c_ = i_ * 256 + tid;                                                        \
        int row_ = c_ >> 3, col8_ = (c_ & 7) ^ (row_ & 7);                              \
        gload16(A + (long)(m0 + row_) * 1024 + (k0) + col8_ * 8,                        \
                (const char*)As[buf] + i_ * 4096 + wid * 1024);                         \
    }                                                                                   \
    _Pragma("unroll") for (int i_ = 0; i_ < 4; ++i_) {                                  \
        int c_ = i_ * 256 + tid;                                                        \
        int row_ = c_ >> 3, col8_ = (c_ & 7) ^ (row_ & 7);                              \
        gload16(Bt + (long)(n0 + row_) * 1024 + (k0) + col8_ * 8,                       \
                (const char*)Bs[buf] + i_ * 4096 + wid * 1024);                         \
    } } while (0)

    f32x4 acc[4][4] = {};
    GSTAGE(0, 0);

    for (int k0 = 0; k0 < 1024; k0 += 64) {
        const int buf = (k0 >> 6) & 1;
        __syncthreads();                       // drains vmcnt(0): buf landed, other buf free
        if (k0 + 64 < 1024) GSTAGE(buf ^ 1, k0 + 64);
#pragma unroll
        for (int kk = 0; kk < 2; ++kk) {
            bf16x8 af[4], bf[4];
#pragma unroll
            for (int mi = 0; mi < 4; ++mi) {
                int row = wr + mi * 16 + l15;
                af[mi] = *(const bf16x8*)(As[buf] + row * 64 + (((kk * 4 + lk) ^ (row & 7)) << 3));
            }
#pragma unroll
            for (int ni = 0; ni < 4; ++ni) {
                int row = wc + ni * 16 + l15;
                bf[ni] = *(const bf16x8*)(Bs[buf] + row * 64 + (((kk * 4 + lk) ^ (row & 7)) << 3));
            }
            __builtin_amdgcn_s_setprio(1);
#pragma unroll
            for (int mi = 0; mi < 4; ++mi)
#pragma unroll
                for (int ni = 0; ni < 4; ++ni)
                    acc[mi][ni] = __builtin_amdgcn_mfma_f32_16x16x32_bf16(af[mi], bf[ni], acc[mi][ni], 0, 0, 0);
            __builtin_amdgcn_s_setprio(0);
        }
    }
#undef GSTAGE

    // epilogue; C/D layout: col = lane&15, row = (lane>>4)*4 + r
#pragma unroll
    for (int mi = 0; mi < 4; ++mi)
#pragma unroll
        for (int ni = 0; ni < 4; ++ni)
#pragma unroll
            for (int r = 0; r < 4; ++r) {
                int row = m0 + wr + mi * 16 + lk * 4 + r;
                int col = n0 + wc + ni * 16 + l15;
                float v = acc[mi][ni][r];
                if (MODE == 0) {
                    if (col < 1024) {            // Q: (+bq +pe) * QSCALE (base-2 domain)
                        v = (v + bq[col] + pe[row * HDIM + (col & 127)]) * QSCALE;
                        Qb[(long)row * 1024 + col] = f2bf(v);
                    } else if (col < 1152) {     // K: +bkv[0:128] +pe
                        int d = col - 1024;
                        v += bkv[d] + pe[row * HDIM + d];
                        Kb[row * HDIM + d] = f2bf(v);
                    } else {                     // V: +bkv[128:256], transposed [d][t]
                        v += bkv[col - 1024];
                        Vtb[(long)(col - 1152) * T_LEN + row] = f2bf(v);
                    }
                } else {
                    Cout[(long)row * 1024 + col] = v;
                }
            }
}

// ---------------- flash attention v8: 456 uniform pieces (<=11 tiles), all co-resident ----------------
// (round 10/11 verified version: 8 waves x 32 queries, 0 bank conflicts, no spills)
__global__ __launch_bounds__(512)
void attn_kernel(const short* __restrict__ Qb, const short* __restrict__ Kb,
                 const short* __restrict__ Vtb, short* __restrict__ Ob,
                 short* __restrict__ opA, short* __restrict__ opB,
                 float* __restrict__ ml) {
    const int tid = threadIdx.x, lane = tid & 63, w = tid >> 6;
    const int q31 = lane & 31, hi = lane >> 5;

    // decode bx -> (j, p, P, mpre): longest rows first (j descending)
    const int bx = blockIdx.x;
    const int q = bx >> 3, h = bx & 7;
    int j = 0, p = 0, mpre = 55, cum = 0;
    for (int jj = 15; jj >= 0; --jj) {
        int Pj = pieces_of(jj);
        if (jj >= 2) mpre -= Pj;               // after this: mpre = sum_{i=2}^{jj-1} P_i
        if (q < cum + Pj) { j = jj; p = q - cum; break; }
        cum += Pj;
    }
    const int P = pieces_of(j);
    const int L = 4 * j + 4;
    const int t0 = (L * p) / P, tend = (L * (p + 1)) / P;
    const int mask_from = (p == P - 1) ? 4 * j : 0x7fffffff;
    const int qw = j * 256 + w * 32;

    __shared__ __align__(16) char Ks[2][64 * 256];    // K [key][16 slots], slot^=(row&15)
    __shared__ __align__(16) char Vts[2][64 * 256];   // V^T [d-pair][16 slots], slot^=(row&15)

    // Q B-frags: col = q31 = query, k = kc*16 + hi*8 + jj. Pre-scaled by QSCALE.
    bf16x8 qf[8];
#pragma unroll
    for (int kc = 0; kc < 8; ++kc)
        qf[kc] = *(const bf16x8*)(Qb + (long)(qw + q31) * 1024 + h * HDIM + kc * 16 + hi * 8);

    f32x16 o[4] = {};
    float m2 = -INFINITY, lsum = 0.f;
    const int kswz = (q31 & 15) << 4;          // K read swizzle (row&15 == q31&15 for both halves)

#define STAGE(buf, kbase) do {                                                          \
    _Pragma("unroll") for (int i_ = 0; i_ < 2; ++i_) {                                  \
        int id_ = (2 * w + i_) * 64 + lane;                                             \
        int ky_ = id_ >> 4, kc_ = id_ & 15;                                             \
        gload16(Kb + (long)((kbase) + ky_) * HDIM + ((kc_ ^ (ky_ & 15)) * 8),           \
                Ks[buf] + (2 * w + i_) * 1024);                                         \
        int vr_ = id_ >> 4, sg_ = (id_ & 15) ^ (vr_ & 15);                              \
        gload16(Vtb + (long)(2 * vr_ + (sg_ >> 3)) * T_LEN + (kbase) + ((sg_ & 7) * 8), \
                Vts[buf] + (2 * w + i_) * 1024);                                        \
    } } while (0)

    STAGE(0, t0 * 64);

    for (int t = t0; t < tend; ++t) {
        const int cur = (t - t0) & 1;
        __syncthreads();                       // vmcnt(0) drain: tile t landed
        if (t + 1 < tend) STAGE(cur ^ 1, (t + 1) * 64);

        // S^T = K @ Q^T : col = q31 = query, row = crow(r,hi) = (r&3)+8*(r>>2)+4*hi
        const char* Kbuf = Ks[cur];
        f32x16 S0 = {}, S1 = {};
        __builtin_amdgcn_s_setprio(1);
#pragma unroll
        for (int kc = 0; kc < 8; ++kc) {
            bf16x8 a0 = *(const bf16x8*)(Kbuf + q31 * 256 + ((kc * 32 + hi * 16) ^ kswz));
            bf16x8 a1 = *(const bf16x8*)(Kbuf + (32 + q31) * 256 + ((kc * 32 + hi * 16) ^ kswz));
            S0 = __builtin_amdgcn_mfma_f32_32x32x16_bf16(a0, qf[kc], S0, 0, 0, 0);
            S1 = __builtin_amdgcn_mfma_f32_32x32x16_bf16(a1, qf[kc], S1, 0, 0, 0);
        }
        __builtin_amdgcn_s_setprio(0);

        if (t >= mask_from) {
            const int query = qw + q31, kb = t * 64 + 4 * hi;
#pragma unroll
            for (int r = 0; r < 16; ++r) {
                int krow = kb + (r & 3) + 8 * (r >> 2);
                if (krow > query)      S0[r] = -1e30f;
                if (krow + 32 > query) S1[r] = -1e30f;
            }
        }

        // defer-max online softmax (base-2); lane pair (q31, q31+32) owns query q31
        float pmax = fmaxf(S0[0], S1[0]);
#pragma unroll
        for (int r = 1; r < 16; ++r) pmax = fmaxf(pmax, fmaxf(S0[r], S1[r]));
        if (!__all(pmax <= m2 + 8.f)) {
            float tm = fmaxf(pmax, __shfl_xor(pmax, 32));
            float nm = fmaxf(m2, tm);
            float sc = __builtin_amdgcn_exp2f(m2 - nm);
            m2 = nm;
            lsum *= sc;
#pragma unroll
            for (int r = 0; r < 16; ++r) {
                float scr = __shfl(sc, (r & 3) + 8 * (r >> 2) + 4 * hi);
                o[0][r] *= scr; o[1][r] *= scr; o[2][r] *= scr; o[3][r] *= scr;
            }
        }

        unsigned pw0[8], pw1[8];
#pragma unroll
        for (int i = 0; i < 8; ++i) {
            float e0 = __builtin_amdgcn_exp2f(S0[2 * i] - m2);
            float e1 = __builtin_amdgcn_exp2f(S0[2 * i + 1] - m2);
            float f0 = __builtin_amdgcn_exp2f(S1[2 * i] - m2);
            float f1 = __builtin_amdgcn_exp2f(S1[2 * i + 1] - m2);
            lsum += (e0 + e1) + (f0 + f1);
            pw0[i] = cvt_pk_bf16(e0, e1);
            pw1[i] = cvt_pk_bf16(f0, f1);
        }
        plswap(pw0[0], pw0[2]); plswap(pw0[1], pw0[3]);
        plswap(pw0[4], pw0[6]); plswap(pw0[5], pw0[7]);
        plswap(pw1[0], pw1[2]); plswap(pw1[1], pw1[3]);
        plswap(pw1[4], pw1[6]); plswap(pw1[5], pw1[7]);
        bf16x8 pfr[4];
        pfr[0] = mk8(pw0[0], pw0[1], pw0[2], pw0[3]);
        pfr[1] = mk8(pw0[4], pw0[5], pw0[6], pw0[7]);
        pfr[2] = mk8(pw1[0], pw1[1], pw1[2], pw1[3]);
        pfr[3] = mk8(pw1[4], pw1[5], pw1[6], pw1[7]);

        // O += P @ V : B-frag for d = dt*32+q31 at V^T LDS row d>>1, slot (d&1)*8+ks*2+hi
        const char* Vbuf = Vts[cur];
        __builtin_amdgcn_s_setprio(1);
#pragma unroll
        for (int ks = 0; ks < 4; ++ks)
#pragma unroll
            for (int dt = 0; dt < 4; ++dt) {
                int d = dt * 32 + q31, vr = d >> 1;
                int slot = ((d & 1) * 8 + ks * 2 + hi) ^ (vr & 15);
                bf16x8 vb = *(const bf16x8*)(Vbuf + vr * 256 + slot * 16);
                o[dt] = __builtin_amdgcn_mfma_f32_32x32x16_bf16(pfr[ks], vb, o[dt], 0, 0, 0);
            }
        __builtin_amdgcn_s_setprio(0);
    }
#undef STAGE

    lsum += __shfl_xor(lsum, 32);              // merge the two key-halves

    if (P == 1) {                              // single piece: normalize + write direct
        float inv = 1.f / lsum;
#pragma unroll
        for (int r = 0; r < 16; ++r) {
            int qrow = (r & 3) + 8 * (r >> 2) + 4 * hi;
            float rl = __shfl(inv, qrow);
            short* dst = Ob + (long)(qw + qrow) * 1024 + h * HDIM + q31;
            dst[0]  = f2bf(o[0][r] * rl);
            dst[32] = f2bf(o[1][r] * rl);
            dst[64] = f2bf(o[2][r] * rl);
            dst[96] = f2bf(o[3][r] * rl);
        }
    } else {                                   // bf16 partial + (m,l)
        const int pidx = (mpre + p) * 8 + h;   // 0..439
        short* Op = (pidx < 208) ? (opA + (long)pidx * 32768)
                                 : (opB + (long)(pidx - 208) * 32768);
#pragma unroll
        for (int r = 0; r < 16; ++r) {
            int qrow = (r & 3) + 8 * (r >> 2) + 4 * hi;
            short* dst = Op + (w * 32 + qrow) * 128 + q31;
            dst[0]  = f2bf(o[0][r]);
            dst[32] = f2bf(o[1][r]);
            dst[64] = f2bf(o[2][r]);
            dst[96] = f2bf(o[3][r]);
        }
        if (hi == 0) {
            float* mlp = ml + ((long)pidx * 256 + w * 32 + q31) * 2;
            mlp[0] = m2; mlp[1] = lsum;
        }
    }
}

// ---------------- combine: merge the P<=6 key-range partials of each multi-piece row ----------------
__global__ __launch_bounds__(256)
void combine_kernel(const short* __restrict__ opA, const short* __restrict__ opB,
                    const float* __restrict__ ml, short* __restrict__ Ob) {
    const int bz = blockIdx.x;                 // 0..223: (j=2..15, h) x 2 query-halves
    const int combo = bz >> 1, qhalf = bz & 1;
    const int j = 2 + (combo >> 3), h = combo & 7;
    const int P = pieces_of(j);
    int mpre = 0;
    for (int i = 2; i < j; ++i) mpre += pieces_of(i);
    const int qq = qhalf * 128 + (threadIdx.x >> 1), dh = (threadIdx.x & 1) * 64;

    float m = -INFINITY, l = 0.f;
    float acc[64];
#pragma unroll
    for (int d = 0; d < 64; ++d) acc[d] = 0.f;

    for (int p = 0; p < P; ++p) {
        const int pidx = (mpre + p) * 8 + h;
        const float* mlp = ml + ((long)pidx * 256 + qq) * 2;
        float mp = mlp[0], lp = mlp[1];
        float nm = fmaxf(m, mp);
        float cA = __builtin_amdgcn_exp2f(m - nm);
        float cB = __builtin_amdgcn_exp2f(mp - nm);
        m = nm;
        l = l * cA + lp * cB;
        const short* Os = ((pidx < 208) ? (opA + (long)pidx * 32768)
                                        : (opB + (long)(pidx - 208) * 32768))
                          + qq * 128 + dh;
#pragma unroll
        for (int c = 0; c < 8; ++c) {
            bf16x8 v = *(const bf16x8*)(Os + c * 8);
#pragma unroll
            for (int e = 0; e < 8; ++e)
                acc[c * 8 + e] = acc[c * 8 + e] * cA + bf2f(v[e]) * cB;
        }
    }
    float inv = 1.f / l;
    short* dst = Ob + (long)(j * 256 + qq) * 1024 + h * HDIM + dh;
#pragma unroll
    for (int c = 0; c < 16; ++c) {
        s16x4 r;
#pragma unroll
        for (int e = 0; e < 4; ++e) r[e] = f2bf(acc[c * 4 + e] * inv);
        *(s16x4*)(dst + c * 4) = r;
    }
}

extern "C" void kernel_launch(void* const* d_in, const int* in_sizes, int n_in,
                              void* d_out, int out_size, void* d_ws, size_t ws_size,
                              hipStream_t stream) {
    const float* x   = (const float*)d_in[0];
    const float* Wq  = (const float*)d_in[1];
    const float* bq  = (const float*)d_in[2];
    const float* Wkv = (const float*)d_in[3];
    const float* bkv = (const float*)d_in[4];
    const float* Wo  = (const float*)d_in[5];
    float* out = (float*)d_out;
    char* ws = (char*)d_ws;

    float* pe   = (float*)(ws);                       // [0, 2MB)
    short* xb   = (short*)(ws + (2l  << 20));         // [2, 10)
    short* wt   = (short*)(ws + (10l << 20));         // [10, 12.5)  (W^T: [n][k])
    short* wot  = (short*)(ws + (13l << 20));         // [13, 15)    (Wo^T)
    short* Qb   = (short*)(ws + (15l << 20));         // [15, 23)
    short* Kb   = (short*)(ws + (23l << 20));         // [23, 24)
    short* Vtb  = (short*)(ws + (24l << 20));         // [24, 25)
    short* Ab   = (short*)(ws + (25l << 20));         // [25, 33)
    // partials: opA overlays pe/xb/wt (dead after gemm<0>, stream-ordered); wot untouched
    short* opA  = (short*)(ws);                       // pieces 0..207   (13MB exactly)
    short* opB  = (short*)(ws + (33l << 20));         // pieces 208..439 (14.5MB)
    float* ml   = (float*)(ws + (95l << 19));         // [47.5, 48.4MB)

    prep_kernel<<<7424, 256, 0, stream>>>(x, Wq, Wkv, Wo, pe, xb, wt, wot);

    gemm_kernel<0><<<dim3(32, 10), 256, 0, stream>>>(xb, wt, bq, bkv, pe,
                                                     Qb, Kb, Vtb, nullptr);
    attn_kernel<<<456, 512, 0, stream>>>(Qb, Kb, Vtb, Ab, opA, opB, ml);
    combine_kernel<<<224, 256, 0, stream>>>(opA, opB, ml, Ab);
    gemm_kernel<1><<<dim3(32, 8), 256, 0, stream>>>(Ab, wot, nullptr, nullptr, nullptr,
                                                    nullptr, nullptr, nullptr, out);
}

// Round 15
// 120.538 us; speedup vs baseline: 1.0886x; 1.0886x over previous
//
#include <hip/hip_runtime.h>
#include <hip/hip_bf16.h>

#define T_LEN 4096
#define EMB   1024
#define HDIM  128
#define QSCALE 0.12752039955379307f   // (1/sqrt(128)) * log2(e) -- folded into Q

typedef __attribute__((ext_vector_type(8))) short bf16x8;
typedef __attribute__((ext_vector_type(4))) short s16x4;
typedef __attribute__((ext_vector_type(4))) float f32x4;
typedef __attribute__((ext_vector_type(16))) float f32x16;
typedef __attribute__((ext_vector_type(4))) unsigned u32x4;

__device__ __forceinline__ short f2bf(float f) {
    unsigned u = __builtin_bit_cast(unsigned, f);
    u += 0x7fffu + ((u >> 16) & 1u);   // RNE
    return (short)(u >> 16);
}
__device__ __forceinline__ float bf2f(short s) {
    unsigned u = ((unsigned)(unsigned short)s) << 16;
    return __builtin_bit_cast(float, u);
}

__device__ __forceinline__ unsigned cvt_pk_bf16(float lo, float hi) {
    unsigned r;
    asm("v_cvt_pk_bf16_f32 %0, %1, %2" : "=v"(r) : "v"(lo), "v"(hi));
    return r;
}

// exchange a.hi32lanes <-> b.lo32lanes (T12)
__device__ __forceinline__ void plswap(unsigned &a, unsigned &b) {
#if __has_builtin(__builtin_amdgcn_permlane32_swap)
    auto r = __builtin_amdgcn_permlane32_swap(a, b, false, false);
    a = r[0]; b = r[1];
#else
    asm volatile("v_permlane32_swap_b32 %0, %1" : "+v"(a), "+v"(b));
#endif
}

__device__ __forceinline__ bf16x8 mk8(unsigned a, unsigned b, unsigned c, unsigned d) {
    u32x4 v = {a, b, c, d};
    return __builtin_bit_cast(bf16x8, v);
}

// async global->LDS DMA, 16B/lane; lds ptr = wave-uniform base (HW adds lane*16)
__device__ __forceinline__ void gload16(const short* g, const char* l) {
    __builtin_amdgcn_global_load_lds(
        (const __attribute__((address_space(1))) unsigned*)g,
        (__attribute__((address_space(3))) unsigned*)l, 16, 0, 0);
}

// pieces for query-row j (256 queries, L=4j+4 key tiles), max 11 tiles/piece
__device__ __forceinline__ int pieces_of(int j) { return (4 * j + 14) / 11; }

// ---------------- fused prep: pe table + x cvt + 3 weight transposes ----------------
__global__ __launch_bounds__(256)
void prep_kernel(const float* __restrict__ x, const float* __restrict__ Wq,
                 const float* __restrict__ Wkv, const float* __restrict__ Wo,
                 float* __restrict__ pe, short* __restrict__ xb,
                 short* __restrict__ wt, short* __restrict__ wot) {
    __shared__ short t[32][33];
    int b = blockIdx.x;
    if (b < 1024) {                            // PE table
        int idx = b * 256 + threadIdx.x;
        int tt = idx >> 6, i = idx & 63;
        float f = __expf(-9.210340371976184f * (float)i / 64.0f);
        float a = (float)tt * f;
        pe[tt * HDIM + 2 * i]     = __sinf(a);
        pe[tt * HDIM + 2 * i + 1] = __cosf(a);
        return;
    }
    b -= 1024;
    if (b < 4096) {                            // x f32 -> bf16
        int e0 = (b * 256 + threadIdx.x) * 4;
        f32x4 v = *(const f32x4*)(x + e0);
        s16x4 o;
        for (int j = 0; j < 4; ++j) o[j] = f2bf(v[j]);
        *(s16x4*)(xb + e0) = o;
        return;
    }
    b -= 4096;                                 // f32 [1024][C] -> bf16 [C][1024]
    const float* src; short* dst; int C, sub;
    if (b < 1024)      { src = Wq;  dst = wt;               C = 1024; sub = b; }
    else if (b < 1280) { src = Wkv; dst = wt + 1024 * 1024; C = 256;  sub = b - 1024; }
    else               { src = Wo;  dst = wot;              C = 1024; sub = b - 1280; }
    const int r0 = (sub & 31) * 32, c0 = (sub >> 5) * 32;
    const int tr = threadIdx.x >> 3, tc4 = (threadIdx.x & 7) * 4;
    f32x4 v = *(const f32x4*)(src + (long)(r0 + tr) * C + c0 + tc4);
    for (int j = 0; j < 4; ++j) t[tc4 + j][tr] = f2bf(v[j]);
    __syncthreads();
    s16x4 o;
    for (int j = 0; j < 4; ++j) o[j] = t[tr][tc4 + j];
    *(s16x4*)(dst + (long)(c0 + tr) * 1024 + r0 + tc4) = o;
}

// ---------------- bf16 MFMA GEMM: 128x64 tile, BK=64, dbuf global_load_lds ----------------
template<int MODE>
__global__ __launch_bounds__(256)
void gemm_kernel(const short* __restrict__ A, const short* __restrict__ Bt,
                 const float* __restrict__ bq, const float* __restrict__ bkv,
                 const float* __restrict__ pe,
                 short* __restrict__ Qb, short* __restrict__ Kb, short* __restrict__ Vtb,
                 float* __restrict__ Cout) {
    const int tid = threadIdx.x, lane = tid & 63, wid = tid >> 6;
    const int l15 = lane & 15, lk = lane >> 4;
    const int m0 = blockIdx.x * 128, n0 = blockIdx.y * 64;
    const int wr = (wid >> 1) * 64, wc = (wid & 1) * 32;

    __shared__ __align__(16) short As[2][128 * 64];   // 16KB per buf
    __shared__ __align__(16) short Bs[2][64 * 64];    // 8KB per buf

#define GSTAGE(buf, k0) do {                                                            \
    _Pragma("unroll") for (int i_ = 0; i_ < 4; ++i_) {                                  \
        int c_ = i_ * 256 + tid;                                                        \
        int row_ = c_ >> 3, col8_ = (c_ & 7) ^ (row_ & 7);                              \
        gload16(A + (long)(m0 + row_) * 1024 + (k0) + col8_ * 8,                        \
                (const char*)As[buf] + i_ * 4096 + wid * 1024);                         \
    }                                                                                   \
    _Pragma("unroll") for (int i_ = 0; i_ < 2; ++i_) {                                  \
        int c_ = i_ * 256 + tid;                                                        \
        int row_ = c_ >> 3, col8_ = (c_ & 7) ^ (row_ & 7);                              \
        gload16(Bt + (long)(n0 + row_) * 1024 + (k0) + col8_ * 8,                       \
                (const char*)Bs[buf] + i_ * 4096 + wid * 1024);                         \
    } } while (0)

    f32x4 acc[4][2] = {};
    GSTAGE(0, 0);

    for (int k0 = 0; k0 < 1024; k0 += 64) {
        const int buf = (k0 >> 6) & 1;
        __syncthreads();                       // drains vmcnt(0): buf landed, other buf free
        if (k0 + 64 < 1024) GSTAGE(buf ^ 1, k0 + 64);
#pragma unroll
        for (int kk = 0; kk < 2; ++kk) {
            bf16x8 af[4], bf[2];
#pragma unroll
            for (int mi = 0; mi < 4; ++mi) {
                int row = wr + mi * 16 + l15;
                af[mi] = *(const bf16x8*)(As[buf] + row * 64 + (((kk * 4 + lk) ^ (row & 7)) << 3));
            }
#pragma unroll
            for (int ni = 0; ni < 2; ++ni) {
                int row = wc + ni * 16 + l15;
                bf[ni] = *(const bf16x8*)(Bs[buf] + row * 64 + (((kk * 4 + lk) ^ (row & 7)) << 3));
            }
            __builtin_amdgcn_s_setprio(1);
#pragma unroll
            for (int mi = 0; mi < 4; ++mi)
#pragma unroll
                for (int ni = 0; ni < 2; ++ni)
                    acc[mi][ni] = __builtin_amdgcn_mfma_f32_16x16x32_bf16(af[mi], bf[ni], acc[mi][ni], 0, 0, 0);
            __builtin_amdgcn_s_setprio(0);
        }
    }
#undef GSTAGE

    // epilogue; C/D layout: col = lane&15, row = (lane>>4)*4 + r
#pragma unroll
    for (int mi = 0; mi < 4; ++mi)
#pragma unroll
        for (int ni = 0; ni < 2; ++ni)
#pragma unroll
            for (int r = 0; r < 4; ++r) {
                int row = m0 + wr + mi * 16 + lk * 4 + r;
                int col = n0 + wc + ni * 16 + l15;
                float v = acc[mi][ni][r];
                if (MODE == 0) {
                    if (col < 1024) {            // Q: (+bq +pe) * QSCALE (base-2 domain)
                        v = (v + bq[col] + pe[row * HDIM + (col & 127)]) * QSCALE;
                        Qb[(long)row * 1024 + col] = f2bf(v);
                    } else if (col < 1152) {     // K: +bkv[0:128] +pe
                        int d = col - 1024;
                        v += bkv[d] + pe[row * HDIM + d];
                        Kb[row * HDIM + d] = f2bf(v);
                    } else {                     // V: +bkv[128:256], transposed [d][t]
                        v += bkv[col - 1024];
                        Vtb[(long)(col - 1152) * T_LEN + row] = f2bf(v);
                    }
                } else {
                    Cout[(long)row * 1024 + col] = v;
                }
            }
}

// ---------------- flash attention v8: 456 uniform pieces (<=11 tiles), all co-resident ----------------
// (round 10/11/13 verified version: 8 waves x 32 queries, 0 bank conflicts, no spills)
__global__ __launch_bounds__(512)
void attn_kernel(const short* __restrict__ Qb, const short* __restrict__ Kb,
                 const short* __restrict__ Vtb, short* __restrict__ Ob,
                 short* __restrict__ opA, short* __restrict__ opB,
                 float* __restrict__ ml) {
    const int tid = threadIdx.x, lane = tid & 63, w = tid >> 6;
    const int q31 = lane & 31, hi = lane >> 5;

    // decode bx -> (j, p, P, mpre): longest rows first (j descending)
    const int bx = blockIdx.x;
    const int q = bx >> 3, h = bx & 7;
    int j = 0, p = 0, mpre = 55, cum = 0;
    for (int jj = 15; jj >= 0; --jj) {
        int Pj = pieces_of(jj);
        if (jj >= 2) mpre -= Pj;               // after this: mpre = sum_{i=2}^{jj-1} P_i
        if (q < cum + Pj) { j = jj; p = q - cum; break; }
        cum += Pj;
    }
    const int P = pieces_of(j);
    const int L = 4 * j + 4;
    const int t0 = (L * p) / P, tend = (L * (p + 1)) / P;
    const int mask_from = (p == P - 1) ? 4 * j : 0x7fffffff;
    const int qw = j * 256 + w * 32;

    __shared__ __align__(16) char Ks[2][64 * 256];    // K [key][16 slots], slot^=(row&15)
    __shared__ __align__(16) char Vts[2][64 * 256];   // V^T [d-pair][16 slots], slot^=(row&15)

    // Q B-frags: col = q31 = query, k = kc*16 + hi*8 + jj. Pre-scaled by QSCALE.
    bf16x8 qf[8];
#pragma unroll
    for (int kc = 0; kc < 8; ++kc)
        qf[kc] = *(const bf16x8*)(Qb + (long)(qw + q31) * 1024 + h * HDIM + kc * 16 + hi * 8);

    f32x16 o[4] = {};
    float m2 = -INFINITY, lsum = 0.f;
    const int kswz = (q31 & 15) << 4;          // K read swizzle (row&15 == q31&15 for both halves)

#define STAGE(buf, kbase) do {                                                          \
    _Pragma("unroll") for (int i_ = 0; i_ < 2; ++i_) {                                  \
        int id_ = (2 * w + i_) * 64 + lane;                                             \
        int ky_ = id_ >> 4, kc_ = id_ & 15;                                             \
        gload16(Kb + (long)((kbase) + ky_) * HDIM + ((kc_ ^ (ky_ & 15)) * 8),           \
                Ks[buf] + (2 * w + i_) * 1024);                                         \
        int vr_ = id_ >> 4, sg_ = (id_ & 15) ^ (vr_ & 15);                              \
        gload16(Vtb + (long)(2 * vr_ + (sg_ >> 3)) * T_LEN + (kbase) + ((sg_ & 7) * 8), \
                Vts[buf] + (2 * w + i_) * 1024);                                        \
    } } while (0)

    STAGE(0, t0 * 64);

    for (int t = t0; t < tend; ++t) {
        const int cur = (t - t0) & 1;
        __syncthreads();                       // vmcnt(0) drain: tile t landed
        if (t + 1 < tend) STAGE(cur ^ 1, (t + 1) * 64);

        // S^T = K @ Q^T : col = q31 = query, row = crow(r,hi) = (r&3)+8*(r>>2)+4*hi
        const char* Kbuf = Ks[cur];
        f32x16 S0 = {}, S1 = {};
        __builtin_amdgcn_s_setprio(1);
#pragma unroll
        for (int kc = 0; kc < 8; ++kc) {
            bf16x8 a0 = *(const bf16x8*)(Kbuf + q31 * 256 + ((kc * 32 + hi * 16) ^ kswz));
            bf16x8 a1 = *(const bf16x8*)(Kbuf + (32 + q31) * 256 + ((kc * 32 + hi * 16) ^ kswz));
            S0 = __builtin_amdgcn_mfma_f32_32x32x16_bf16(a0, qf[kc], S0, 0, 0, 0);
            S1 = __builtin_amdgcn_mfma_f32_32x32x16_bf16(a1, qf[kc], S1, 0, 0, 0);
        }
        __builtin_amdgcn_s_setprio(0);

        if (t >= mask_from) {
            const int query = qw + q31, kb = t * 64 + 4 * hi;
#pragma unroll
            for (int r = 0; r < 16; ++r) {
                int krow = kb + (r & 3) + 8 * (r >> 2);
                if (krow > query)      S0[r] = -1e30f;
                if (krow + 32 > query) S1[r] = -1e30f;
            }
        }

        // defer-max online softmax (base-2); lane pair (q31, q31+32) owns query q31
        float pmax = fmaxf(S0[0], S1[0]);
#pragma unroll
        for (int r = 1; r < 16; ++r) pmax = fmaxf(pmax, fmaxf(S0[r], S1[r]));
        if (!__all(pmax <= m2 + 8.f)) {
            float tm = fmaxf(pmax, __shfl_xor(pmax, 32));
            float nm = fmaxf(m2, tm);
            float sc = __builtin_amdgcn_exp2f(m2 - nm);
            m2 = nm;
            lsum *= sc;
#pragma unroll
            for (int r = 0; r < 16; ++r) {
                float scr = __shfl(sc, (r & 3) + 8 * (r >> 2) + 4 * hi);
                o[0][r] *= scr; o[1][r] *= scr; o[2][r] *= scr; o[3][r] *= scr;
            }
        }

        unsigned pw0[8], pw1[8];
#pragma unroll
        for (int i = 0; i < 8; ++i) {
            float e0 = __builtin_amdgcn_exp2f(S0[2 * i] - m2);
            float e1 = __builtin_amdgcn_exp2f(S0[2 * i + 1] - m2);
            float f0 = __builtin_amdgcn_exp2f(S1[2 * i] - m2);
            float f1 = __builtin_amdgcn_exp2f(S1[2 * i + 1] - m2);
            lsum += (e0 + e1) + (f0 + f1);
            pw0[i] = cvt_pk_bf16(e0, e1);
            pw1[i] = cvt_pk_bf16(f0, f1);
        }
        plswap(pw0[0], pw0[2]); plswap(pw0[1], pw0[3]);
        plswap(pw0[4], pw0[6]); plswap(pw0[5], pw0[7]);
        plswap(pw1[0], pw1[2]); plswap(pw1[1], pw1[3]);
        plswap(pw1[4], pw1[6]); plswap(pw1[5], pw1[7]);
        bf16x8 pfr[4];
        pfr[0] = mk8(pw0[0], pw0[1], pw0[2], pw0[3]);
        pfr[1] = mk8(pw0[4], pw0[5], pw0[6], pw0[7]);
        pfr[2] = mk8(pw1[0], pw1[1], pw1[2], pw1[3]);
        pfr[3] = mk8(pw1[4], pw1[5], pw1[6], pw1[7]);

        // O += P @ V : B-frag for d = dt*32+q31 at V^T LDS row d>>1, slot (d&1)*8+ks*2+hi
        const char* Vbuf = Vts[cur];
        __builtin_amdgcn_s_setprio(1);
#pragma unroll
        for (int ks = 0; ks < 4; ++ks)
#pragma unroll
            for (int dt = 0; dt < 4; ++dt) {
                int d = dt * 32 + q31, vr = d >> 1;
                int slot = ((d & 1) * 8 + ks * 2 + hi) ^ (vr & 15);
                bf16x8 vb = *(const bf16x8*)(Vbuf + vr * 256 + slot * 16);
                o[dt] = __builtin_amdgcn_mfma_f32_32x32x16_bf16(pfr[ks], vb, o[dt], 0, 0, 0);
            }
        __builtin_amdgcn_s_setprio(0);
    }
#undef STAGE

    lsum += __shfl_xor(lsum, 32);              // merge the two key-halves

    if (P == 1) {                              // single piece: normalize + write direct
        float inv = 1.f / lsum;
#pragma unroll
        for (int r = 0; r < 16; ++r) {
            int qrow = (r & 3) + 8 * (r >> 2) + 4 * hi;
            float rl = __shfl(inv, qrow);
            short* dst = Ob + (long)(qw + qrow) * 1024 + h * HDIM + q31;
            dst[0]  = f2bf(o[0][r] * rl);
            dst[32] = f2bf(o[1][r] * rl);
            dst[64] = f2bf(o[2][r] * rl);
            dst[96] = f2bf(o[3][r] * rl);
        }
    } else {                                   // bf16 partial + (m,l)
        const int pidx = (mpre + p) * 8 + h;   // 0..439
        short* Op = (pidx < 208) ? (opA + (long)pidx * 32768)
                                 : (opB + (long)(pidx - 208) * 32768);
#pragma unroll
        for (int r = 0; r < 16; ++r) {
            int qrow = (r & 3) + 8 * (r >> 2) + 4 * hi;
            short* dst = Op + (w * 32 + qrow) * 128 + q31;
            dst[0]  = f2bf(o[0][r]);
            dst[32] = f2bf(o[1][r]);
            dst[64] = f2bf(o[2][r]);
            dst[96] = f2bf(o[3][r]);
        }
        if (hi == 0) {
            float* mlp = ml + ((long)pidx * 256 + w * 32 + q31) * 2;
            mlp[0] = m2; mlp[1] = lsum;
        }
    }
}

// ---------------- combine: merge the P<=6 key-range partials of each multi-piece row ----------------
__global__ __launch_bounds__(256)
void combine_kernel(const short* __restrict__ opA, const short* __restrict__ opB,
                    const float* __restrict__ ml, short* __restrict__ Ob) {
    const int bz = blockIdx.x;                 // 0..223: (j=2..15, h) x 2 query-halves
    const int combo = bz >> 1, qhalf = bz & 1;
    const int j = 2 + (combo >> 3), h = combo & 7;
    const int P = pieces_of(j);
    int mpre = 0;
    for (int i = 2; i < j; ++i) mpre += pieces_of(i);
    const int qq = qhalf * 128 + (threadIdx.x >> 1), dh = (threadIdx.x & 1) * 64;

    float m = -INFINITY, l = 0.f;
    float acc[64];
#pragma unroll
    for (int d = 0; d < 64; ++d) acc[d] = 0.f;

    for (int p = 0; p < P; ++p) {
        const int pidx = (mpre + p) * 8 + h;
        const float* mlp = ml + ((long)pidx * 256 + qq) * 2;
        float mp = mlp[0], lp = mlp[1];
        float nm = fmaxf(m, mp);
        float cA = __builtin_amdgcn_exp2f(m - nm);
        float cB = __builtin_amdgcn_exp2f(mp - nm);
        m = nm;
        l = l * cA + lp * cB;
        const short* Os = ((pidx < 208) ? (opA + (long)pidx * 32768)
                                        : (opB + (long)(pidx - 208) * 32768))
                          + qq * 128 + dh;
#pragma unroll
        for (int c = 0; c < 8; ++c) {
            bf16x8 v = *(const bf16x8*)(Os + c * 8);
#pragma unroll
            for (int e = 0; e < 8; ++e)
                acc[c * 8 + e] = acc[c * 8 + e] * cA + bf2f(v[e]) * cB;
        }
    }
    float inv = 1.f / l;
    short* dst = Ob + (long)(j * 256 + qq) * 1024 + h * HDIM + dh;
#pragma unroll
    for (int c = 0; c < 16; ++c) {
        s16x4 r;
#pragma unroll
        for (int e = 0; e < 4; ++e) r[e] = f2bf(acc[c * 4 + e] * inv);
        *(s16x4*)(dst + c * 4) = r;
    }
}

extern "C" void kernel_launch(void* const* d_in, const int* in_sizes, int n_in,
                              void* d_out, int out_size, void* d_ws, size_t ws_size,
                              hipStream_t stream) {
    const float* x   = (const float*)d_in[0];
    const float* Wq  = (const float*)d_in[1];
    const float* bq  = (const float*)d_in[2];
    const float* Wkv = (const float*)d_in[3];
    const float* bkv = (const float*)d_in[4];
    const float* Wo  = (const float*)d_in[5];
    float* out = (float*)d_out;
    char* ws = (char*)d_ws;

    float* pe   = (float*)(ws);                       // [0, 2MB)
    short* xb   = (short*)(ws + (2l  << 20));         // [2, 10)
    short* wt   = (short*)(ws + (10l << 20));         // [10, 12.5)  (W^T: [n][k])
    short* wot  = (short*)(ws + (13l << 20));         // [13, 15)    (Wo^T)
    short* Qb   = (short*)(ws + (15l << 20));         // [15, 23)
    short* Kb   = (short*)(ws + (23l << 20));         // [23, 24)
    short* Vtb  = (short*)(ws + (24l << 20));         // [24, 25)
    short* Ab   = (short*)(ws + (25l << 20));         // [25, 33)
    // partials: opA overlays pe/xb/wt (dead after gemm<0>, stream-ordered); wot untouched
    short* opA  = (short*)(ws);                       // pieces 0..207   (13MB exactly)
    short* opB  = (short*)(ws + (33l << 20));         // pieces 208..439 (14.5MB)
    float* ml   = (float*)(ws + (95l << 19));         // [47.5, 48.4MB)

    prep_kernel<<<7424, 256, 0, stream>>>(x, Wq, Wkv, Wo, pe, xb, wt, wot);

    gemm_kernel<0><<<dim3(32, 20), 256, 0, stream>>>(xb, wt, bq, bkv, pe,
                                                     Qb, Kb, Vtb, nullptr);
    attn_kernel<<<456, 512, 0, stream>>>(Qb, Kb, Vtb, Ab, opA, opB, ml);
    combine_kernel<<<224, 256, 0, stream>>>(opA, opB, ml, Ab);
    gemm_kernel<1><<<dim3(32, 16), 256, 0, stream>>>(Ab, wot, nullptr, nullptr, nullptr,
                                                     nullptr, nullptr, nullptr, out);
}